// Round 1
// 490.238 us; speedup vs baseline: 1.2490x; 1.2490x over previous
//
#include <hip/hip_runtime.h>

// Depthwise(3x3, rank-1) + pointwise(256x128) conv, fp32 in/out.
// B=16, C=128, H=W=128, OUT=256.
//
// Two-dispatch split (latency fix for the fused kernel's 2%-MFMA/11%-VALU idle):
//   dw_rows: depthwise one (b,h) row -> bf16 y, transposed [w][c] + XOR swizzle,
//            dumped as raw bytes into scratch = bytes of out[b][0:64][h][:].
//            Low VGPR + 32KiB LDS -> ~4 blocks/CU, latency hidden by TLP.
//   pw_gemm: stages y rows via global_load_lds (4 x dwordx4/thread, double-
//            buffered, issued before previous row's MFMA), then the identical
//            MFMA GEMM + store. Overwrites the scratch region after staging.
// Per-(b,h) scratch slices are disjoint across blocks; stream ordering makes
// kernel-1 writes visible to kernel-2. No d_ws dependency.
#define BB 16
#define CC 128
#define HH 128
#define WW 128
#define OO 256
#define RR 4               // h rows per gemm block
#define HW (HH * WW)

typedef float f32x4 __attribute__((ext_vector_type(4)));
typedef unsigned int u32x4 __attribute__((ext_vector_type(4)));
typedef short bf16x8 __attribute__((ext_vector_type(8)));

__device__ __forceinline__ unsigned short f2bf(float f) {
    unsigned int u = __float_as_uint(f);
    unsigned int r = (u + 0x7FFFu + ((u >> 16) & 1u)) >> 16;
    return (unsigned short)r;
}

__device__ __forceinline__ void gload_lds16(const void* g, void* l) {
    __builtin_amdgcn_global_load_lds(
        (const __attribute__((address_space(1))) void*)g,
        (__attribute__((address_space(3))) void*)l,
        16, 0, 0);
}

// ---------------------------------------------------------------------------
// Kernel 1: depthwise. grid = B*H = 2048 blocks, 512 threads.
// Math is bit-identical to the verified fused kernel's phase1.
// ---------------------------------------------------------------------------
__global__ __launch_bounds__(512, 4)
void dw_rows(const float* __restrict__ x,
             const float* __restrict__ colk,
             const float* __restrict__ rowk,
             float* __restrict__ out)
{
    __shared__ __align__(16) unsigned short ybuf[WW][CC];   // 32 KiB

    const int tid  = threadIdx.x;
    const int blk  = blockIdx.x;
    const int b    = blk >> 7;            // 16
    const int hrow = blk & (HH - 1);      // 128

    const int wph = tid & 127;            // w position (coalesced x)
    const int cg  = tid >> 7;             // 0..3, wave-uniform -> scalar weights
    const size_t base_b = (size_t)b * CC * HW;

    const bool hm  = (hrow > 0);
    const bool hp  = (hrow < HH - 1);
    const bool wmv = (wph > 0);
    const bool wpv = (wph < WW - 1);
    #pragma unroll 2
    for (int ci = 0; ci < 16; ++ci) {               // channel pairs
        unsigned int pack = 0;
        #pragma unroll
        for (int t = 0; t < 2; ++t) {
            const int c = cg * 32 + ci * 2 + t;
            const float* xr = x + base_b + ((size_t)c * HH + hrow) * WW + wph;
            const float c0k = colk[c * 3 + 0];
            const float c1k = colk[c * 3 + 1];
            const float c2k = colk[c * 3 + 2];
            const float r0k = rowk[c * 3 + 0];
            const float r1k = rowk[c * 3 + 1];
            const float r2k = rowk[c * 3 + 2];
            float acc;
            {   // center x-row always valid
                const float xm = wmv ? xr[-1] : 0.0f;
                const float xc = xr[0];
                const float xp = wpv ? xr[1] : 0.0f;
                acc = c1k * (r0k * xm + r1k * xc + r2k * xp);
            }
            if (hm) {
                const float* p = xr - WW;
                const float xm = wmv ? p[-1] : 0.0f;
                const float xc = p[0];
                const float xp = wpv ? p[1] : 0.0f;
                acc += c0k * (r0k * xm + r1k * xc + r2k * xp);
            }
            if (hp) {
                const float* p = xr + WW;
                const float xm = wmv ? p[-1] : 0.0f;
                const float xc = p[0];
                const float xp = wpv ? p[1] : 0.0f;
                acc += c2k * (r0k * xm + r1k * xc + r2k * xp);
            }
            pack |= (unsigned int)f2bf(acc) << (16 * t);
        }
        // transposed store y[w][c], swizzle 16B group: g' = g ^ (w&15)
        const int c = cg * 32 + ci * 2;
        const int csw = (((c >> 3) ^ (wph & 15)) << 3) | (c & 7);
        *(unsigned int*)&ybuf[wph][csw] = pack;
    }

    __syncthreads();

    // Dump ybuf (32 KiB) -> scratch bytes of out[b][o=chunk][hrow][:], fully
    // coalesced. 2048 16B-units; unit idx: chunk = idx>>5 (one 512B out-row
    // per chunk), slot = idx&31.
    float* ob = out + (size_t)b * OO * HW + (size_t)hrow * WW;
    const u32x4* src = (const u32x4*)&ybuf[0][0];
    #pragma unroll
    for (int p = 0; p < 4; ++p) {
        const int idx   = p * 512 + tid;
        const int chunk = idx >> 5;
        const int slot  = idx & 31;
        const u32x4 v = src[idx];
        *(u32x4*)((char*)(ob + (size_t)chunk * HW) + slot * 16) = v;
    }
}

// ---------------------------------------------------------------------------
// Kernel 2: pointwise GEMM. grid = B*(H/RR) = 512 blocks, 512 threads.
// out[o][w] = sum_c pw[o][c]*y[c][w] via mfma_f32_16x16x32_bf16 (identical
// fragment code to the verified fused kernel).
// ---------------------------------------------------------------------------
__global__ __launch_bounds__(512, 2)
void pw_gemm(const float* __restrict__ pw,
             float* __restrict__ out)
{
    __shared__ __align__(16) unsigned short ybuf[2][WW][CC];   // 64 KiB

    const int tid  = threadIdx.x;
    const int lane = tid & 63;
    const int wave = tid >> 6;          // 0..7
    const int la   = lane & 15;         // MFMA n/m lane index
    const int qa   = lane >> 4;         // MFMA quad 0..3
    const int mg   = wave >> 1;         // o-group: o base = mg*64
    const int ng   = wave & 1;          // w-group: w base = ng*64

    const int blk = blockIdx.x;
    const int b   = blk >> 5;           // 16 b values
    const int h0  = (blk & 31) * RR;    // 32 strips of RR rows

    // ---------- A fragments: pw -> bf16 registers (once per block) ----------
    bf16x8 afrag[4][4];
    {
        #pragma unroll
        for (int ot = 0; ot < 4; ++ot) {
            const float* prow = pw + (size_t)(mg * 64 + ot * 16 + la) * CC;
            #pragma unroll
            for (int ks = 0; ks < 4; ++ks) {
                const int c0 = ks * 32 + qa * 8;
                const float4 f0 = *(const float4*)(prow + c0);
                const float4 f1 = *(const float4*)(prow + c0 + 4);
                bf16x8 a;
                a[0] = (short)f2bf(f0.x); a[1] = (short)f2bf(f0.y);
                a[2] = (short)f2bf(f0.z); a[3] = (short)f2bf(f0.w);
                a[4] = (short)f2bf(f1.x); a[5] = (short)f2bf(f1.y);
                a[6] = (short)f2bf(f1.z); a[7] = (short)f2bf(f1.w);
                afrag[ot][ks] = a;
            }
        }
    }

    // ---------- stage: y row (scratch bytes) -> LDS, linear, async ----------
    auto stage = [&](int hrow, int buf) {
        const char* gb = (const char*)(out + (size_t)b * OO * HW
                                           + (size_t)hrow * WW);
        #pragma unroll
        for (int p = 0; p < 4; ++p) {
            const int U     = p * 512 + wave * 64;   // wave-uniform 16B-unit base
            const int idx   = U + lane;
            const int chunk = idx >> 5;
            const int slot  = idx & 31;
            const void* srcp = gb + (size_t)chunk * (HW * 4) + slot * 16;
            // LDS dest: uniform base, HW adds lane*16 (linear layout)
            gload_lds16(srcp, &ybuf[buf][U >> 4][0]);
        }
    };

    // ---------- gemm: one row out[o][w] += pw * y ----------
    auto gemm = [&](int hrow, int buf) {
        f32x4 acc[4][4];
        #pragma unroll
        for (int ot = 0; ot < 4; ++ot)
            #pragma unroll
            for (int wt = 0; wt < 4; ++wt)
                acc[ot][wt] = (f32x4){0.f, 0.f, 0.f, 0.f};

        #pragma unroll
        for (int ks = 0; ks < 4; ++ks) {
            bf16x8 bfr[4];
            const int g = ks * 4 + qa;              // c group index c0>>3
            #pragma unroll
            for (int wt = 0; wt < 4; ++wt) {
                const int w = ng * 64 + wt * 16 + la;
                const int csw = (g ^ la) << 3;      // w&15 == la
                bfr[wt] = *(const bf16x8*)&ybuf[buf][w][csw];
            }
            #pragma unroll
            for (int wt = 0; wt < 4; ++wt)
                #pragma unroll
                for (int ot = 0; ot < 4; ++ot)
                    acc[ot][wt] = __builtin_amdgcn_mfma_f32_16x16x32_bf16(
                        afrag[ot][ks], bfr[wt], acc[ot][wt], 0, 0, 0);
        }

        // D[row = qa*4 + r][col = la]; store 4 o-rows per fragment
        const size_t outb = (size_t)b * OO * HW + (size_t)hrow * WW;
        #pragma unroll
        for (int ot = 0; ot < 4; ++ot) {
            const int o = mg * 64 + ot * 16 + qa * 4;
            #pragma unroll
            for (int wt = 0; wt < 4; ++wt) {
                const int w = ng * 64 + wt * 16 + la;
                float* op = out + outb + (size_t)o * HW + w;
                op[0 * HW] = acc[ot][wt][0];
                op[1 * HW] = acc[ot][wt][1];
                op[2 * HW] = acc[ot][wt][2];
                op[3 * HW] = acc[ot][wt][3];
            }
        }
    };

    // ---------- main loop: stage(r+1) issued before gemm(r) (async) ----------
    stage(h0, 0);
    #pragma unroll 1
    for (int r = 0; r < RR; ++r) {
        // stage(r) complete (own-wave), then block-wide
        asm volatile("s_waitcnt vmcnt(0)" ::: "memory");
        __syncthreads();
        // safe: gemm(r-1) finished reading buf[(r+1)&1] before the barrier
        if (r + 1 < RR) stage(h0 + r + 1, (r + 1) & 1);
        gemm(h0 + r, r & 1);
    }
}

extern "C" void kernel_launch(void* const* d_in, const int* in_sizes, int n_in,
                              void* d_out, int out_size, void* d_ws, size_t ws_size,
                              hipStream_t stream) {
    const float* x    = (const float*)d_in[0];   // (16,128,128,128)
    const float* colk = (const float*)d_in[1];   // (128,1,3,1)
    const float* rowk = (const float*)d_in[2];   // (128,1,1,3)
    const float* pw   = (const float*)d_in[3];   // (256,128)
    float* out = (float*)d_out;                  // (16,256,128,128)

    hipLaunchKernelGGL(dw_rows, dim3(BB * HH), dim3(512), 0, stream,
                       x, colk, rowk, out);
    hipLaunchKernelGGL(pw_gemm, dim3(BB * (HH / RR)), dim3(512), 0, stream,
                       pw, out);
}

// Round 2
// 430.787 us; speedup vs baseline: 1.4213x; 1.1380x over previous
//
#include <hip/hip_runtime.h>

// Depthwise(3x3, rank-1) + pointwise(256x128) conv, fp32 in/out.
// B=16, C=128, H=W=128, OUT=256.
//
// Two-dispatch split:
//   dw_rows: depthwise one (b,h) row -> bf16 y, transposed [w][c] + XOR swizzle,
//            dumped as raw bytes into scratch = bytes of out[b][0:64][h][:].
//            float4 over w + shfl for the +-1 taps (4x fewer mem instrs).
//   pw_gemm: stages y rows via global_load_lds (double-buffered, issued before
//            previous row's MFMA), MFMA with swapped operands so D is
//            w-contiguous -> dwordx4 non-temporal stores.
// Per-(b,h) scratch slices are disjoint across blocks; stream ordering makes
// kernel-1 writes visible to kernel-2.
#define BB 16
#define CC 128
#define HH 128
#define WW 128
#define OO 256
#define RR 4               // h rows per gemm block
#define HW (HH * WW)

typedef float f32x4 __attribute__((ext_vector_type(4)));
typedef unsigned int u32x4 __attribute__((ext_vector_type(4)));
typedef short bf16x8 __attribute__((ext_vector_type(8)));

__device__ __forceinline__ unsigned short f2bf(float f) {
    unsigned int u = __float_as_uint(f);
    unsigned int r = (u + 0x7FFFu + ((u >> 16) & 1u)) >> 16;
    return (unsigned short)r;
}

__device__ __forceinline__ void gload_lds16(const void* g, void* l) {
    __builtin_amdgcn_global_load_lds(
        (const __attribute__((address_space(1))) void*)g,
        (__attribute__((address_space(3))) void*)l,
        16, 0, 0);
}

// ---------------------------------------------------------------------------
// Kernel 1: depthwise. grid = B*H = 2048 blocks, 512 threads.
// Thread = 4 consecutive w (float4) x 8 channels. +-1 w taps come from
// __shfl of the center vector (edge lanes masked to 0 by w-predicates,
// matching padding). Math per element identical to the verified kernel.
// ---------------------------------------------------------------------------
__global__ __launch_bounds__(512, 4)
void dw_rows(const float* __restrict__ x,
             const float* __restrict__ colk,
             const float* __restrict__ rowk,
             float* __restrict__ out)
{
    __shared__ __align__(16) unsigned short ybuf[WW][CC];   // 32 KiB

    const int tid  = threadIdx.x;
    const int blk  = blockIdx.x;
    const int b    = blk >> 7;            // 16
    const int hrow = blk & (HH - 1);      // 128

    const int wq = tid & 31;              // w-quad: w = wq*4 .. wq*4+3
    const int cb = tid >> 5;              // 0..15, 8 channels each
    const int w0 = wq * 4;
    const size_t base_b = (size_t)b * CC * HW;

    const bool hm     = (hrow > 0);
    const bool hp     = (hrow < HH - 1);
    const bool wfirst = (wq == 0);        // needs w=-1 -> 0
    const bool wlast  = (wq == 31);       // needs w=128 -> 0

    #pragma unroll
    for (int i = 0; i < 4; ++i) {         // channel pairs within this cb
        unsigned int pack[4] = {0u, 0u, 0u, 0u};
        #pragma unroll
        for (int t = 0; t < 2; ++t) {
            const int c = cb * 8 + i * 2 + t;
            const float* xr = x + base_b + ((size_t)c * HH + hrow) * WW + w0;
            const float c0k = colk[c * 3 + 0];
            const float c1k = colk[c * 3 + 1];
            const float c2k = colk[c * 3 + 2];
            const float r0k = rowk[c * 3 + 0];
            const float r1k = rowk[c * 3 + 1];
            const float r2k = rowk[c * 3 + 2];
            float acc0, acc1, acc2, acc3;
            {   // center row always valid
                const float4 v = *(const float4*)xr;
                const float lm = __shfl_up(v.w, 1);
                const float rn = __shfl_down(v.x, 1);
                const float xm0 = wfirst ? 0.0f : lm;
                const float xp3 = wlast  ? 0.0f : rn;
                acc0 = c1k * (r0k * xm0 + r1k * v.x + r2k * v.y);
                acc1 = c1k * (r0k * v.x + r1k * v.y + r2k * v.z);
                acc2 = c1k * (r0k * v.y + r1k * v.z + r2k * v.w);
                acc3 = c1k * (r0k * v.z + r1k * v.w + r2k * xp3);
            }
            if (hm) {
                const float4 v = *(const float4*)(xr - WW);
                const float lm = __shfl_up(v.w, 1);
                const float rn = __shfl_down(v.x, 1);
                const float xm0 = wfirst ? 0.0f : lm;
                const float xp3 = wlast  ? 0.0f : rn;
                acc0 += c0k * (r0k * xm0 + r1k * v.x + r2k * v.y);
                acc1 += c0k * (r0k * v.x + r1k * v.y + r2k * v.z);
                acc2 += c0k * (r0k * v.y + r1k * v.z + r2k * v.w);
                acc3 += c0k * (r0k * v.z + r1k * v.w + r2k * xp3);
            }
            if (hp) {
                const float4 v = *(const float4*)(xr + WW);
                const float lm = __shfl_up(v.w, 1);
                const float rn = __shfl_down(v.x, 1);
                const float xm0 = wfirst ? 0.0f : lm;
                const float xp3 = wlast  ? 0.0f : rn;
                acc0 += c2k * (r0k * xm0 + r1k * v.x + r2k * v.y);
                acc1 += c2k * (r0k * v.x + r1k * v.y + r2k * v.z);
                acc2 += c2k * (r0k * v.y + r1k * v.z + r2k * v.w);
                acc3 += c2k * (r0k * v.z + r1k * v.w + r2k * xp3);
            }
            const unsigned int sh = 16 * t;
            pack[0] |= (unsigned int)f2bf(acc0) << sh;
            pack[1] |= (unsigned int)f2bf(acc1) << sh;
            pack[2] |= (unsigned int)f2bf(acc2) << sh;
            pack[3] |= (unsigned int)f2bf(acc3) << sh;
        }
        // transposed store y[w][c], swizzle 16B group: g' = g ^ (w&15)
        const int c0 = cb * 8 + i * 2;
        #pragma unroll
        for (int k = 0; k < 4; ++k) {
            const int w = w0 + k;
            const int csw = (((c0 >> 3) ^ (w & 15)) << 3) | (c0 & 7);
            *(unsigned int*)&ybuf[w][csw] = pack[k];
        }
    }

    __syncthreads();

    // Dump ybuf (32 KiB) -> scratch bytes of out[b][o=chunk][hrow][:], fully
    // coalesced. 2048 16B-units; chunk = idx>>5 (one 512B out-row per chunk).
    float* ob = out + (size_t)b * OO * HW + (size_t)hrow * WW;
    const u32x4* src = (const u32x4*)&ybuf[0][0];
    #pragma unroll
    for (int p = 0; p < 4; ++p) {
        const int idx   = p * 512 + tid;
        const int chunk = idx >> 5;
        const int slot  = idx & 31;
        const u32x4 v = src[idx];
        *(u32x4*)((char*)(ob + (size_t)chunk * HW) + slot * 16) = v;
    }
}

// ---------------------------------------------------------------------------
// Kernel 2: pointwise GEMM. grid = B*(H/RR) = 512 blocks, 512 threads.
// out[o][w] = sum_c pw[o][c]*y[c][w]. Operands swapped vs round-0 kernel:
// A = y (m=w), B = pw (n=o) -> D regs are w-contiguous -> dwordx4 stores.
// ---------------------------------------------------------------------------
__global__ __launch_bounds__(512, 2)
void pw_gemm(const float* __restrict__ pw,
             float* __restrict__ out)
{
    __shared__ __align__(16) unsigned short ybuf[2][WW][CC];   // 64 KiB

    const int tid  = threadIdx.x;
    const int lane = tid & 63;
    const int wave = tid >> 6;          // 0..7
    const int la   = lane & 15;         // MFMA n/m lane index
    const int qa   = lane >> 4;         // MFMA quad 0..3
    const int mg   = wave >> 1;         // o-group: o base = mg*64
    const int ng   = wave & 1;          // w-group: w base = ng*64

    const int blk = blockIdx.x;
    const int b   = blk >> 5;           // 16 b values
    const int h0  = (blk & 31) * RR;    // 32 strips of RR rows

    // ---------- pw fragments (B operand): lane la holds pw[o][c0..c0+7] ----
    bf16x8 afrag[4][4];
    {
        #pragma unroll
        for (int ot = 0; ot < 4; ++ot) {
            const float* prow = pw + (size_t)(mg * 64 + ot * 16 + la) * CC;
            #pragma unroll
            for (int ks = 0; ks < 4; ++ks) {
                const int c0 = ks * 32 + qa * 8;
                const float4 f0 = *(const float4*)(prow + c0);
                const float4 f1 = *(const float4*)(prow + c0 + 4);
                bf16x8 a;
                a[0] = (short)f2bf(f0.x); a[1] = (short)f2bf(f0.y);
                a[2] = (short)f2bf(f0.z); a[3] = (short)f2bf(f0.w);
                a[4] = (short)f2bf(f1.x); a[5] = (short)f2bf(f1.y);
                a[6] = (short)f2bf(f1.z); a[7] = (short)f2bf(f1.w);
                afrag[ot][ks] = a;
            }
        }
    }

    // ---------- stage: y row (scratch bytes) -> LDS, linear, async ----------
    auto stage = [&](int hrow, int buf) {
        const char* gb = (const char*)(out + (size_t)b * OO * HW
                                           + (size_t)hrow * WW);
        #pragma unroll
        for (int p = 0; p < 4; ++p) {
            const int U     = p * 512 + wave * 64;   // wave-uniform 16B-unit base
            const int idx   = U + lane;
            const int chunk = idx >> 5;
            const int slot  = idx & 31;
            const void* srcp = gb + (size_t)chunk * (HW * 4) + slot * 16;
            gload_lds16(srcp, &ybuf[buf][U >> 4][0]);
        }
    };

    // ---------- gemm: one row, A=y B=pw, w-contiguous D ----------
    auto gemm = [&](int hrow, int buf) {
        f32x4 acc[4][4];
        #pragma unroll
        for (int ot = 0; ot < 4; ++ot)
            #pragma unroll
            for (int wt = 0; wt < 4; ++wt)
                acc[ot][wt] = (f32x4){0.f, 0.f, 0.f, 0.f};

        #pragma unroll
        for (int ks = 0; ks < 4; ++ks) {
            bf16x8 bfr[4];
            const int g = ks * 4 + qa;              // c group index c0>>3
            #pragma unroll
            for (int wt = 0; wt < 4; ++wt) {
                const int w = ng * 64 + wt * 16 + la;
                const int csw = (g ^ la) << 3;      // w&15 == la
                bfr[wt] = *(const bf16x8*)&ybuf[buf][w][csw];
            }
            #pragma unroll
            for (int wt = 0; wt < 4; ++wt)
                #pragma unroll
                for (int ot = 0; ot < 4; ++ot)
                    acc[ot][wt] = __builtin_amdgcn_mfma_f32_16x16x32_bf16(
                        bfr[wt], afrag[ot][ks], acc[ot][wt], 0, 0, 0);
        }

        // D[row = qa*4 + r -> w][col = la -> o]; 16B store per fragment
        const size_t outb = (size_t)b * OO * HW + (size_t)hrow * WW;
        #pragma unroll
        for (int ot = 0; ot < 4; ++ot) {
            const int o = mg * 64 + ot * 16 + la;
            #pragma unroll
            for (int wt = 0; wt < 4; ++wt) {
                const int w = ng * 64 + wt * 16 + qa * 4;
                float* op = out + outb + (size_t)o * HW + w;
                __builtin_nontemporal_store(acc[ot][wt], (f32x4*)op);
            }
        }
    };

    // ---------- main loop: stage(r+1) issued before gemm(r) (async) ----------
    stage(h0, 0);
    #pragma unroll 1
    for (int r = 0; r < RR; ++r) {
        asm volatile("s_waitcnt vmcnt(0)" ::: "memory");
        __syncthreads();
        if (r + 1 < RR) stage(h0 + r + 1, (r + 1) & 1);
        gemm(h0 + r, r & 1);
    }
}

extern "C" void kernel_launch(void* const* d_in, const int* in_sizes, int n_in,
                              void* d_out, int out_size, void* d_ws, size_t ws_size,
                              hipStream_t stream) {
    const float* x    = (const float*)d_in[0];   // (16,128,128,128)
    const float* colk = (const float*)d_in[1];   // (128,1,3,1)
    const float* rowk = (const float*)d_in[2];   // (128,1,1,3)
    const float* pw   = (const float*)d_in[3];   // (256,128)
    float* out = (float*)d_out;                  // (16,256,128,128)

    hipLaunchKernelGGL(dw_rows, dim3(BB * HH), dim3(512), 0, stream,
                       x, colk, rowk, out);
    hipLaunchKernelGGL(pw_gemm, dim3(BB * (HH / RR)), dim3(512), 0, stream,
                       pw, out);
}